// Round 4
// baseline (181.666 us; speedup 1.0000x reference)
//
#include <hip/hip_runtime.h>
#include <hip/hip_bf16.h>

// RetinaNet heads on MI355X: implicit-GEMM bf16 MFMA conv3x3.
// Block = 128 consecutive flat output positions (per pyramid level) x 80 (padded 78) out chans.
// 4 waves; wave = [80 x 32] via 5 M-tiles x 2 N-tiles of v_mfma_f32_16x16x32_bf16.
// K-loop: 4 channel-chunks (64) x 3 kh x 3 kw. Input rows staged once per chunk (shared
// across kh). Weights prepacked to d_ws (bf16, pre-swizzled, contiguous per (chunk,kh,kw)),
// double-buffered in LDS via register prefetch.
// [R3: fix — __builtin_bit_cast on __hip_bfloat16x is not trivially copyable on this ROCm;
//  replaced with manual RNE f32->bf16 bit arithmetic (same numerics for non-NaN data)]

typedef float  f32x4  __attribute__((ext_vector_type(4)));
typedef short  bf16x8 __attribute__((ext_vector_type(8)));   // 8 x bf16 (guide-verified operand type)
typedef int    i32x4  __attribute__((ext_vector_type(4)));

#define TOTAL_ANCH 32760            // 6 * sum(HW)
#define BBOX_TOTAL 2096640          // 16*4*32760
#define PW_BYTES   1474560          // 2 heads * 36 blocks * 10240 B
#define NB_MAIN    683

// f32 -> bf16 with round-to-nearest-even (matches __float2bfloat16 for non-NaN)
__device__ __forceinline__ unsigned short f2bf(float f) {
    unsigned u = __float_as_uint(f);
    return (unsigned short)((u + 0x7FFFu + ((u >> 16) & 1u)) >> 16);
}

__device__ __forceinline__ unsigned pack2(float a, float b) {
    return (unsigned)f2bf(a) | ((unsigned)f2bf(b) << 16);
}

// ---------------- prepack: weights -> bf16, layout [head][chunk][kh][kw][o:80][b:8][e:8]
// with per-row pre-swizzle b_stored = b_logical ^ (o&7) so the main kernel's swizzled
// ds_read_b128 lands on contiguous channels. Bias packed as fp32 [head][80].
__global__ void retina_prepack(
    const float* __restrict__ wr1, const float* __restrict__ br1,
    const float* __restrict__ wc1, const float* __restrict__ bc1,
    const float* __restrict__ wr2, const float* __restrict__ br2,
    const float* __restrict__ wc2, const float* __restrict__ bc2,
    unsigned short* __restrict__ PW, float* __restrict__ PB)
{
    int g = blockIdx.x * 256 + threadIdx.x;
    if (g < 737280) {
        int e = g & 7;
        int b = (g >> 3) & 7;
        int q = g >> 6;            // (((head*4+chunk)*3+kh)*3+kw)*80 + o
        int o = q % 80;
        int rest = q / 80;
        int kw = rest % 3; rest /= 3;
        int kh = rest % 3; rest /= 3;
        int chunk = rest & 3;
        int head  = rest >> 2;
        float v = 0.f;
        if (o < 78) {
            int c = (chunk << 6) + ((b ^ (o & 7)) << 3) + e;   // pre-swizzled source channel
            const float* wsrc; int oo;
            if (o < 24) { wsrc = head ? wr2 : wr1; oo = o; }
            else        { wsrc = head ? wc2 : wc1; oo = o - 24; }
            v = wsrc[((oo * 256 + c) * 3 + kh) * 3 + kw];
        }
        PW[g] = f2bf(v);
    }
    if (g < 160) {
        int head = g / 80, o = g % 80;
        float bv = 0.f;
        if (o < 24)      bv = (head ? br2 : br1)[o];
        else if (o < 78) bv = (head ? bc2 : bc1)[o - 24];
        PB[g] = bv;
    }
}

// ---------------- main conv kernel
__global__ __launch_bounds__(256, 2) void retina_main(
    const float* __restrict__ f0, const float* __restrict__ f1,
    const float* __restrict__ f2, const float* __restrict__ f3,
    const float* __restrict__ f4, const float* __restrict__ f5,
    const unsigned short* __restrict__ PW, const float* __restrict__ PB,
    float* __restrict__ out)
{
    // X region: 256 rows x 128 B (rows = slot*W + w, 64 bf16 chans, XOR-swizzled 16B blocks)
    // W region: 2 x 10240 B double buffer ([o:80][128 B])
    __shared__ __align__(16) char lds[32768 + 2 * 10240];

    const int tid = threadIdx.x;
    const int bid = blockIdx.x;

    int lvl, tile;
    if      (bid < 512) { lvl = 0; tile = bid;       }
    else if (bid < 640) { lvl = 1; tile = bid - 512; }
    else if (bid < 672) { lvl = 2; tile = bid - 640; }
    else if (bid < 680) { lvl = 3; tile = bid - 672; }
    else if (bid < 682) { lvl = 4; tile = bid - 680; }
    else                { lvl = 5; tile = 0;         }

    const int logW  = 6 - lvl;          // H == W per level
    const int W     = 1 << logW;
    const int H     = W;
    const int logHW = 2 * logW;
    const int HW    = 1 << logHW;
    const int NHW   = 16 << logHW;

    const int nrowsTab[6] = {4, 6, 10, 18, 34, 34};          // tile rows + 2 halo
    const int offlTab[6]  = {0, 24576, 30720, 32256, 32640, 32736};
    const int S    = nrowsTab[lvl];
    const int offl = offlTab[lvl];
    const float* x = (lvl == 0) ? f0 : (lvl == 1) ? f1 : (lvl == 2) ? f2
                   : (lvl == 3) ? f3 : (lvl == 4) ? f4 : f5;
    const int head = (lvl < 2) ? 0 : 1;

    const int p0 = tile << 7;           // first flat position of tile
    const int r0 = p0 >> logW;          // first flat row

    const int l   = tid & 63;
    const int wv  = tid >> 6;
    const int lg  = l >> 4;
    const int l16 = l & 15;

    int rlocal[2], wpos[2], hrow[2];
    #pragma unroll
    for (int nt = 0; nt < 2; ++nt) {
        int tpos   = wv * 32 + nt * 16 + l16;
        rlocal[nt] = tpos >> logW;
        wpos[nt]   = tpos & (W - 1);
        hrow[nt]   = (r0 + rlocal[nt]) & (H - 1);
    }

    f32x4 acc[5][2];
    {
        f32x4 zf = {0.f, 0.f, 0.f, 0.f};
        #pragma unroll
        for (int m = 0; m < 5; ++m) { acc[m][0] = zf; acc[m][1] = zf; }
    }

    // A-fragment byte offsets within W buffer (o = m*16 + l16; swizzle uses o&7 == l16&7)
    const int axor  = l16 & 7;
    const int aoff0 = l16 * 128 + ((lg       ^ axor) << 4);
    const int aoff1 = l16 * 128 + (((4 + lg) ^ axor) << 4);

    const char* pwbase = (const char*)PW + (size_t)head * 368640;   // 36 * 10240

    // stage one channel-chunk of input rows [r0-1 .. r0+S-2] into X region (bf16, swizzled)
    auto stageX = [&](int chunk) {
        const int items = S << (logW + 3);          // S * 8 blocks * W
        for (int e = tid; e < items; e += 256) {
            int w = e & (W - 1);
            int b = (e >> logW) & 7;
            int s = e >> (logW + 3);
            int vr = r0 - 1 + s;                    // flat global row (content; masking at read)
            i32x4 val = {0, 0, 0, 0};
            if ((unsigned)vr < (unsigned)(16 << logW)) {
                int n  = vr >> logW;
                int h  = vr & (H - 1);
                int c0 = (chunk << 6) + (b << 3);
                const float* src = x + (size_t)(((n << 8) + c0) << logHW) + (h << logW) + w;
                float v0 = src[0];          float v1 = src[(size_t)HW];
                float v2 = src[(size_t)2*HW]; float v3 = src[(size_t)3*HW];
                float v4 = src[(size_t)4*HW]; float v5 = src[(size_t)5*HW];
                float v6 = src[(size_t)6*HW]; float v7 = src[(size_t)7*HW];
                val[0] = (int)pack2(v0, v1);
                val[1] = (int)pack2(v2, v3);
                val[2] = (int)pack2(v4, v5);
                val[3] = (int)pack2(v6, v7);
            }
            int rowidx = (s << logW) + w;
            int boff   = rowidx * 128 + ((b ^ (rowidx & 7)) << 4);
            *(i32x4*)(lds + boff) = val;
        }
    };

    // prologue: X chunk0 + W block 0
    stageX(0);
    {
        const i32x4* s = (const i32x4*)pwbase;
        i32x4 a = s[tid];
        i32x4 b = s[tid + 256];
        i32x4 c;
        if (tid < 128) c = s[tid + 512];
        char* d = lds + 32768;
        *(i32x4*)(d + tid * 16)         = a;
        *(i32x4*)(d + (tid + 256) * 16) = b;
        if (tid < 128) *(i32x4*)(d + (tid + 512) * 16) = c;
    }
    __syncthreads();

    for (int chunk = 0; chunk < 4; ++chunk) {
        if (chunk) { stageX(chunk); __syncthreads(); }
        #pragma unroll
        for (int t9 = 0; t9 < 9; ++t9) {
            const int kh   = t9 / 3;
            const int kw   = t9 % 3;
            const int cidx = chunk * 9 + t9;

            // prefetch next W block into registers (double buffer)
            i32x4 pa, pb, pc;
            const bool have = (cidx + 1) < 36;
            if (have) {
                const i32x4* s = (const i32x4*)(pwbase + (size_t)(cidx + 1) * 10240);
                pa = s[tid];
                pb = s[tid + 256];
                if (tid < 128) pc = s[tid + 512];
            }

            // B fragments (input), with image-boundary (kh) + row-edge (kw) masking
            bf16x8 bfr[2][2];
            #pragma unroll
            for (int nt = 0; nt < 2; ++nt) {
                int wp  = wpos[nt] + kw - 1;
                bool ok = ((unsigned)(hrow[nt] + kh - 1) < (unsigned)H)
                       && ((unsigned)wp < (unsigned)W);
                int wc = wp < 0 ? 0 : (wp >= W ? W - 1 : wp);
                int rowidx = ((rlocal[nt] + kh) << logW) + wc;
                int rsw = rowidx & 7;
                const char* bp = lds + rowidx * 128;
                bfr[nt][0] = *(const bf16x8*)(bp + ((lg       ^ rsw) << 4));
                bfr[nt][1] = *(const bf16x8*)(bp + (((4 + lg) ^ rsw) << 4));
                if (!ok) {
                    bf16x8 z = {0, 0, 0, 0, 0, 0, 0, 0};
                    bfr[nt][0] = z;
                    bfr[nt][1] = z;
                }
            }

            // land prefetched W block into the other buffer
            if (have) {
                char* d = lds + 32768 + ((cidx + 1) & 1) * 10240;
                *(i32x4*)(d + tid * 16)         = pa;
                *(i32x4*)(d + (tid + 256) * 16) = pb;
                if (tid < 128) *(i32x4*)(d + (tid + 512) * 16) = pc;
            }

            // 20 MFMAs: 5 M-tiles x 2 N-tiles x K=64 (2 steps of 32)
            const char* wb = lds + 32768 + (cidx & 1) * 10240;
            #pragma unroll
            for (int m = 0; m < 5; ++m) {
                bf16x8 a0 = *(const bf16x8*)(wb + m * 2048 + aoff0);
                bf16x8 a1 = *(const bf16x8*)(wb + m * 2048 + aoff1);
                acc[m][0] = __builtin_amdgcn_mfma_f32_16x16x32_bf16(a0, bfr[0][0], acc[m][0], 0, 0, 0);
                acc[m][0] = __builtin_amdgcn_mfma_f32_16x16x32_bf16(a1, bfr[0][1], acc[m][0], 0, 0, 0);
                acc[m][1] = __builtin_amdgcn_mfma_f32_16x16x32_bf16(a0, bfr[1][0], acc[m][1], 0, 0, 0);
                acc[m][1] = __builtin_amdgcn_mfma_f32_16x16x32_bf16(a1, bfr[1][1], acc[m][1], 0, 0, 0);
            }
            __syncthreads();
        }
    }

    // epilogue: bias + scatter to reshape/concat layout.
    // D tile: col = lane&15 (position), row = lg*4 + r (out channel within 16-tile)
    const float* bias = PB + head * 80;
    #pragma unroll
    for (int nt = 0; nt < 2; ++nt) {
        int pos = p0 + wv * 32 + nt * 16 + l16;
        if (pos >= NHW) continue;                   // only level 5 partial tile
        int n   = pos >> logHW;
        int rem = pos & (HW - 1);
        int base0 = offl + rem;
        #pragma unroll
        for (int m = 0; m < 5; ++m) {
            #pragma unroll
            for (int r = 0; r < 4; ++r) {
                int o = m * 16 + lg * 4 + r;
                if (o < 78) {
                    float v = acc[m][nt][r] + bias[o];
                    int idx;
                    if (o < 24) {
                        int g = o / 6, a = o - g * 6;
                        idx = (n * 4 + g) * TOTAL_ANCH + base0 + (a << logHW);
                    } else {
                        int cc = o - 24;
                        int k = cc / 6, a = cc - k * 6;
                        idx = BBOX_TOTAL + (n * 9 + k) * TOTAL_ANCH + base0 + (a << logHW);
                    }
                    out[idx] = v;
                }
            }
        }
    }
}

extern "C" void kernel_launch(void* const* d_in, const int* in_sizes, int n_in,
                              void* d_out, int out_size, void* d_ws, size_t ws_size,
                              hipStream_t stream) {
    const float* f0  = (const float*)d_in[0];
    const float* f1  = (const float*)d_in[1];
    const float* f2  = (const float*)d_in[2];
    const float* f3  = (const float*)d_in[3];
    const float* f4  = (const float*)d_in[4];
    const float* f5  = (const float*)d_in[5];
    const float* wr1 = (const float*)d_in[6];
    const float* br1 = (const float*)d_in[7];
    const float* wc1 = (const float*)d_in[8];
    const float* bc1 = (const float*)d_in[9];
    const float* wr2 = (const float*)d_in[10];
    const float* br2 = (const float*)d_in[11];
    const float* wc2 = (const float*)d_in[12];
    const float* bc2 = (const float*)d_in[13];

    unsigned short* PW = (unsigned short*)d_ws;
    float*          PB = (float*)((char*)d_ws + PW_BYTES);

    retina_prepack<<<2880, 256, 0, stream>>>(wr1, br1, wc1, bc1, wr2, br2, wc2, bc2, PW, PB);
    retina_main<<<NB_MAIN, 256, 0, stream>>>(f0, f1, f2, f3, f4, f5, PW, PB, (float*)d_out);
}

// Round 5
// 178.596 us; speedup vs baseline: 1.0172x; 1.0172x over previous
//
#include <hip/hip_runtime.h>
#include <hip/hip_bf16.h>

// RetinaNet heads on MI355X: implicit-GEMM bf16 MFMA conv3x3.
// Block = 128 consecutive flat output positions (per pyramid level) x 80 (padded 78) out chans.
// 4 waves; wave = [80 x 32] via 5 M-tiles x 2 N-tiles of v_mfma_f32_16x16x32_bf16.
// K-loop: 4 channel-chunks (64) x 3 kh x 3 kw. Input rows staged once per chunk (shared
// across kh). Weights prepacked to d_ws (bf16, pre-swizzled, contiguous per (chunk,kh,kw)).
// [R4: weight staging reg-roundtrip -> __builtin_amdgcn_global_load_lds width=16.
//  Loads for step i+1 issued at top of step i, drained by end-of-step barrier's vmcnt(0);
//  MFMA covers L2 latency. Removes the per-step vmcnt stall that made all pipes <25%.]

typedef float  f32x4  __attribute__((ext_vector_type(4)));
typedef short  bf16x8 __attribute__((ext_vector_type(8)));   // 8 x bf16 (guide-verified operand type)
typedef int    i32x4  __attribute__((ext_vector_type(4)));

#define TOTAL_ANCH 32760            // 6 * sum(HW)
#define BBOX_TOTAL 2096640          // 16*4*32760
#define PW_BYTES   1474560          // 2 heads * 36 blocks * 10240 B
#define NB_MAIN    683

// f32 -> bf16 with round-to-nearest-even (matches __float2bfloat16 for non-NaN)
__device__ __forceinline__ unsigned short f2bf(float f) {
    unsigned u = __float_as_uint(f);
    return (unsigned short)((u + 0x7FFFu + ((u >> 16) & 1u)) >> 16);
}

__device__ __forceinline__ unsigned pack2(float a, float b) {
    return (unsigned)f2bf(a) | ((unsigned)f2bf(b) << 16);
}

// async global->LDS, 16 B per lane; LDS dest = wave-uniform base + lane*16
__device__ __forceinline__ void gload16(const void* g, void* l) {
    __builtin_amdgcn_global_load_lds(
        (const __attribute__((address_space(1))) void*)g,
        (__attribute__((address_space(3))) void*)l, 16, 0, 0);
}

// ---------------- prepack: weights -> bf16, layout [head][chunk][kh][kw][o:80][b:8][e:8]
// with per-row pre-swizzle b_stored = b_logical ^ (o&7) so the main kernel's swizzled
// ds_read_b128 lands on contiguous channels. Bias packed as fp32 [head][80].
__global__ void retina_prepack(
    const float* __restrict__ wr1, const float* __restrict__ br1,
    const float* __restrict__ wc1, const float* __restrict__ bc1,
    const float* __restrict__ wr2, const float* __restrict__ br2,
    const float* __restrict__ wc2, const float* __restrict__ bc2,
    unsigned short* __restrict__ PW, float* __restrict__ PB)
{
    int g = blockIdx.x * 256 + threadIdx.x;
    if (g < 737280) {
        int e = g & 7;
        int b = (g >> 3) & 7;
        int q = g >> 6;            // (((head*4+chunk)*3+kh)*3+kw)*80 + o
        int o = q % 80;
        int rest = q / 80;
        int kw = rest % 3; rest /= 3;
        int kh = rest % 3; rest /= 3;
        int chunk = rest & 3;
        int head  = rest >> 2;
        float v = 0.f;
        if (o < 78) {
            int c = (chunk << 6) + ((b ^ (o & 7)) << 3) + e;   // pre-swizzled source channel
            const float* wsrc; int oo;
            if (o < 24) { wsrc = head ? wr2 : wr1; oo = o; }
            else        { wsrc = head ? wc2 : wc1; oo = o - 24; }
            v = wsrc[((oo * 256 + c) * 3 + kh) * 3 + kw];
        }
        PW[g] = f2bf(v);
    }
    if (g < 160) {
        int head = g / 80, o = g % 80;
        float bv = 0.f;
        if (o < 24)      bv = (head ? br2 : br1)[o];
        else if (o < 78) bv = (head ? bc2 : bc1)[o - 24];
        PB[g] = bv;
    }
}

// ---------------- main conv kernel
__global__ __launch_bounds__(256, 2) void retina_main(
    const float* __restrict__ f0, const float* __restrict__ f1,
    const float* __restrict__ f2, const float* __restrict__ f3,
    const float* __restrict__ f4, const float* __restrict__ f5,
    const unsigned short* __restrict__ PW, const float* __restrict__ PB,
    float* __restrict__ out)
{
    // X region: 256 rows x 128 B (rows = slot*W + w, 64 bf16 chans, XOR-swizzled 16B blocks)
    // W region: 2 x 10240 B double buffer ([o:80][128 B])
    __shared__ __align__(16) char lds[32768 + 2 * 10240];

    const int tid = threadIdx.x;
    const int bid = blockIdx.x;

    int lvl, tile;
    if      (bid < 512) { lvl = 0; tile = bid;       }
    else if (bid < 640) { lvl = 1; tile = bid - 512; }
    else if (bid < 672) { lvl = 2; tile = bid - 640; }
    else if (bid < 680) { lvl = 3; tile = bid - 672; }
    else if (bid < 682) { lvl = 4; tile = bid - 680; }
    else                { lvl = 5; tile = 0;         }

    const int logW  = 6 - lvl;          // H == W per level
    const int W     = 1 << logW;
    const int H     = W;
    const int logHW = 2 * logW;
    const int HW    = 1 << logHW;
    const int NHW   = 16 << logHW;

    const int nrowsTab[6] = {4, 6, 10, 18, 34, 34};          // tile rows + 2 halo
    const int offlTab[6]  = {0, 24576, 30720, 32256, 32640, 32736};
    const int S    = nrowsTab[lvl];
    const int offl = offlTab[lvl];
    const float* x = (lvl == 0) ? f0 : (lvl == 1) ? f1 : (lvl == 2) ? f2
                   : (lvl == 3) ? f3 : (lvl == 4) ? f4 : f5;
    const int head = (lvl < 2) ? 0 : 1;

    const int p0 = tile << 7;           // first flat position of tile
    const int r0 = p0 >> logW;          // first flat row

    const int l   = tid & 63;
    const int wv  = tid >> 6;
    const int lg  = l >> 4;
    const int l16 = l & 15;

    int rlocal[2], wpos[2], hrow[2];
    #pragma unroll
    for (int nt = 0; nt < 2; ++nt) {
        int tpos   = wv * 32 + nt * 16 + l16;
        rlocal[nt] = tpos >> logW;
        wpos[nt]   = tpos & (W - 1);
        hrow[nt]   = (r0 + rlocal[nt]) & (H - 1);
    }

    f32x4 acc[5][2];
    {
        f32x4 zf = {0.f, 0.f, 0.f, 0.f};
        #pragma unroll
        for (int m = 0; m < 5; ++m) { acc[m][0] = zf; acc[m][1] = zf; }
    }

    // A-fragment byte offsets within W buffer (o = m*16 + l16; swizzle uses o&7 == l16&7)
    const int axor  = l16 & 7;
    const int aoff0 = l16 * 128 + ((lg       ^ axor) << 4);
    const int aoff1 = l16 * 128 + (((4 + lg) ^ axor) << 4);

    const char* pwbase = (const char*)PW + (size_t)head * 368640;   // 36 * 10240

    // W-block async stage: wave wv covers bytes [wv*2560, wv*2560+2560) of a 10240-B block.
    // Per wave: 2 full 1KB gload16 calls + 1 half call (lanes 0-31). LDS dest linear.
    auto stageW = [&](int cidx, int buf) {
        const char* src = pwbase + (size_t)cidx * 10240 + wv * 2560 + l * 16;
        char*       dst = lds + 32768 + buf * 10240 + wv * 2560;
        gload16(src,        dst);
        gload16(src + 1024, dst + 1024);
        if (l < 32) gload16(src + 2048, dst + 2048);
    };

    // stage one channel-chunk of input rows [r0-1 .. r0+S-2] into X region (bf16, swizzled)
    auto stageX = [&](int chunk) {
        const int items = S << (logW + 3);          // S * 8 blocks * W
        for (int e = tid; e < items; e += 256) {
            int w = e & (W - 1);
            int b = (e >> logW) & 7;
            int s = e >> (logW + 3);
            int vr = r0 - 1 + s;                    // flat global row (content; masking at read)
            i32x4 val = {0, 0, 0, 0};
            if ((unsigned)vr < (unsigned)(16 << logW)) {
                int n  = vr >> logW;
                int h  = vr & (H - 1);
                int c0 = (chunk << 6) + (b << 3);
                const float* src = x + (size_t)(((n << 8) + c0) << logHW) + (h << logW) + w;
                float v0 = src[0];          float v1 = src[(size_t)HW];
                float v2 = src[(size_t)2*HW]; float v3 = src[(size_t)3*HW];
                float v4 = src[(size_t)4*HW]; float v5 = src[(size_t)5*HW];
                float v6 = src[(size_t)6*HW]; float v7 = src[(size_t)7*HW];
                val[0] = (int)pack2(v0, v1);
                val[1] = (int)pack2(v2, v3);
                val[2] = (int)pack2(v4, v5);
                val[3] = (int)pack2(v6, v7);
            }
            int rowidx = (s << logW) + w;
            int boff   = rowidx * 128 + ((b ^ (rowidx & 7)) << 4);
            *(i32x4*)(lds + boff) = val;
        }
    };

    // prologue: X chunk0 + W block 0 (async; barrier drains vmcnt)
    stageW(0, 0);
    stageX(0);
    __syncthreads();

    for (int chunk = 0; chunk < 4; ++chunk) {
        if (chunk) { stageX(chunk); __syncthreads(); }
        #pragma unroll
        for (int t9 = 0; t9 < 9; ++t9) {
            const int kh   = t9 / 3;
            const int kw   = t9 % 3;
            const int cidx = chunk * 9 + t9;

            // async-prefetch next W block into the other LDS buffer (in flight during MFMA)
            if (cidx + 1 < 36) stageW(cidx + 1, (cidx + 1) & 1);

            // B fragments (input), with image-boundary (kh) + row-edge (kw) masking
            bf16x8 bfr[2][2];
            #pragma unroll
            for (int nt = 0; nt < 2; ++nt) {
                int wp  = wpos[nt] + kw - 1;
                bool ok = ((unsigned)(hrow[nt] + kh - 1) < (unsigned)H)
                       && ((unsigned)wp < (unsigned)W);
                int wc = wp < 0 ? 0 : (wp >= W ? W - 1 : wp);
                int rowidx = ((rlocal[nt] + kh) << logW) + wc;
                int rsw = rowidx & 7;
                const char* bp = lds + rowidx * 128;
                bfr[nt][0] = *(const bf16x8*)(bp + ((lg       ^ rsw) << 4));
                bfr[nt][1] = *(const bf16x8*)(bp + (((4 + lg) ^ rsw) << 4));
                if (!ok) {
                    bf16x8 z = {0, 0, 0, 0, 0, 0, 0, 0};
                    bfr[nt][0] = z;
                    bfr[nt][1] = z;
                }
            }

            // 20 MFMAs: 5 M-tiles x 2 N-tiles x K=64 (2 steps of 32)
            const char* wb = lds + 32768 + (cidx & 1) * 10240;
            #pragma unroll
            for (int m = 0; m < 5; ++m) {
                bf16x8 a0 = *(const bf16x8*)(wb + m * 2048 + aoff0);
                bf16x8 a1 = *(const bf16x8*)(wb + m * 2048 + aoff1);
                acc[m][0] = __builtin_amdgcn_mfma_f32_16x16x32_bf16(a0, bfr[0][0], acc[m][0], 0, 0, 0);
                acc[m][0] = __builtin_amdgcn_mfma_f32_16x16x32_bf16(a1, bfr[0][1], acc[m][0], 0, 0, 0);
                acc[m][1] = __builtin_amdgcn_mfma_f32_16x16x32_bf16(a0, bfr[1][0], acc[m][1], 0, 0, 0);
                acc[m][1] = __builtin_amdgcn_mfma_f32_16x16x32_bf16(a1, bfr[1][1], acc[m][1], 0, 0, 0);
            }
            __syncthreads();   // also drains the in-flight W prefetch (vmcnt(0) before barrier)
        }
    }

    // epilogue: bias + scatter to reshape/concat layout.
    // D tile: col = lane&15 (position), row = lg*4 + r (out channel within 16-tile)
    const float* bias = PB + head * 80;
    #pragma unroll
    for (int nt = 0; nt < 2; ++nt) {
        int pos = p0 + wv * 32 + nt * 16 + l16;
        if (pos >= NHW) continue;                   // only level 5 partial tile
        int n   = pos >> logHW;
        int rem = pos & (HW - 1);
        int base0 = offl + rem;
        #pragma unroll
        for (int m = 0; m < 5; ++m) {
            #pragma unroll
            for (int r = 0; r < 4; ++r) {
                int o = m * 16 + lg * 4 + r;
                if (o < 78) {
                    float v = acc[m][nt][r] + bias[o];
                    int idx;
                    if (o < 24) {
                        int g = o / 6, a = o - g * 6;
                        idx = (n * 4 + g) * TOTAL_ANCH + base0 + (a << logHW);
                    } else {
                        int cc = o - 24;
                        int k = cc / 6, a = cc - k * 6;
                        idx = BBOX_TOTAL + (n * 9 + k) * TOTAL_ANCH + base0 + (a << logHW);
                    }
                    out[idx] = v;
                }
            }
        }
    }
}

extern "C" void kernel_launch(void* const* d_in, const int* in_sizes, int n_in,
                              void* d_out, int out_size, void* d_ws, size_t ws_size,
                              hipStream_t stream) {
    const float* f0  = (const float*)d_in[0];
    const float* f1  = (const float*)d_in[1];
    const float* f2  = (const float*)d_in[2];
    const float* f3  = (const float*)d_in[3];
    const float* f4  = (const float*)d_in[4];
    const float* f5  = (const float*)d_in[5];
    const float* wr1 = (const float*)d_in[6];
    const float* br1 = (const float*)d_in[7];
    const float* wc1 = (const float*)d_in[8];
    const float* bc1 = (const float*)d_in[9];
    const float* wr2 = (const float*)d_in[10];
    const float* br2 = (const float*)d_in[11];
    const float* wc2 = (const float*)d_in[12];
    const float* bc2 = (const float*)d_in[13];

    unsigned short* PW = (unsigned short*)d_ws;
    float*          PB = (float*)((char*)d_ws + PW_BYTES);

    retina_prepack<<<2880, 256, 0, stream>>>(wr1, br1, wc1, bc1, wr2, br2, wc2, bc2, PW, PB);
    retina_main<<<NB_MAIN, 256, 0, stream>>>(f0, f1, f2, f3, f4, f5, PW, PB, (float*)d_out);
}